// Round 5
// baseline (1839.281 us; speedup 1.0000x reference)
//
#include <hip/hip_runtime.h>

// Single-pass stable stream compaction, HIERARCHICAL decoupled lookback.
// y[:count] = x[x>0] in original order, y[count:n] = 0, y[out_size-1] = (float)count.
//
// R1 (measured): waiting on inclusive prefixes = serial 16K-hop chain (1956us).
// R4 (measured): flat AGG-only lookback = O(numBlocks^2)=134M atomic flag loads,
//                64-deep dependent L3 walks (995us, 6% HBM).
// Fix: two-level flags. GROUP=256 blocks. Last-publishing member of each group
// (found via gcount fetch_add) sums its group's 256 valid flags -> gflags[g].
// Block b sums: gflags[0..g) (one per thread, <=63) + own partial group's
// level-0 flags (one per thread, <=255). Sequential depth ~2 loads, total
// flag transactions ~5M (28x less).
//
// Ticket order == execution start order -> predecessors resident-or-retired
// -> all spins terminate regardless of dispatch order. Valid bit + value
// packed in one 32-bit word -> relaxed polls are sound; publishes use
// release / acq_rel RMW (release sequence) for flag-value visibility.

#define BLOCK 256
#define VPT 16               // elems per thread (contiguous)
#define CHUNK (BLOCK * VPT)  // 4096
#define GROUP 256            // blocks per group (numBlocks <= 65536 supported)
#define FLAG_VALID 0x80000000u
#define FLAG_MASK  0x7FFFFFFFu

__global__ void k_init(unsigned int* __restrict__ ws, int nWords) {
    const int i = blockIdx.x * BLOCK + threadIdx.x;
    if (i < nWords) ws[i] = 0u;
}

__global__ void __launch_bounds__(BLOCK)
k_compact(const float* __restrict__ x, int n, int numBlocks, int numGroups, int out_size,
          unsigned int* __restrict__ flags, float* __restrict__ y) {
    unsigned int* gflags = flags + numBlocks;
    unsigned int* gcount = gflags + numGroups;
    unsigned int* ticket = gcount + numGroups;

    __shared__ __align__(16) float vals[CHUNK + 4];  // +pad (<=3) for aligned output
    __shared__ int lds[16];  // [0..3] quick totals, [4..7] scan tails,
                             // [8..11] lookback sums, [12..15] group-sum reduce
    __shared__ unsigned int s_bid;
    __shared__ int s_last;

    const int tid  = threadIdx.x;
    const int lane = tid & 63;
    const int wave = tid >> 6;

    if (tid == 0) s_bid = atomicAdd(ticket, 1u);
    __syncthreads();
    const int b = (int)s_bid;
    const int chunkBase = b * CHUNK;
    const long long tbase = (long long)chunkBase + (long long)tid * VPT;

    float v[VPT];
    if ((long long)chunkBase + CHUNK <= n) {
#pragma unroll
        for (int k = 0; k < 4; ++k) {
            const float4 f = *reinterpret_cast<const float4*>(x + tbase + 4 * k);
            v[4 * k + 0] = f.x; v[4 * k + 1] = f.y; v[4 * k + 2] = f.z; v[4 * k + 3] = f.w;
        }
    } else {
#pragma unroll
        for (int j = 0; j < VPT; ++j)
            v[j] = (tbase + j < n) ? x[tbase + j] : 0.f;
    }

    int c = 0;
#pragma unroll
    for (int j = 0; j < VPT; ++j) c += (v[j] > 0.f);

    // Quick block total -> publish level-0 aggregate ASAP.
    int t64 = c;
#pragma unroll
    for (int off = 32; off > 0; off >>= 1) t64 += __shfl_down(t64, off, 64);
    if (lane == 0) lds[wave] = t64;
    __syncthreads();
    const int total = lds[0] + lds[1] + lds[2] + lds[3];
    if (tid == 0) {
        __hip_atomic_store(&flags[b], FLAG_VALID | (unsigned)total,
                           __ATOMIC_RELEASE, __HIP_MEMORY_SCOPE_AGENT);
    }

    // Group duty: last-publishing member sums the group and publishes gflags[g].
    const int g     = b >> 8;
    const int gBase = g << 8;
    const int gSize = (numBlocks - gBase < GROUP) ? (numBlocks - gBase) : GROUP;
    if (tid == 0) {
        const unsigned old = __hip_atomic_fetch_add(&gcount[g], 1u,
                                 __ATOMIC_ACQ_REL, __HIP_MEMORY_SCOPE_AGENT);
        s_last = (old == (unsigned)(gSize - 1));
    }
    __syncthreads();
    if (s_last) {   // block-uniform
        int gs = 0;
        if (tid < gSize) {
            const unsigned f = __hip_atomic_load(&flags[gBase + tid],
                                   __ATOMIC_RELAXED, __HIP_MEMORY_SCOPE_AGENT);
            gs = (int)(f & FLAG_MASK);
        }
#pragma unroll
        for (int off = 32; off > 0; off >>= 1) gs += __shfl_down(gs, off, 64);
        if (lane == 0) lds[12 + wave] = gs;
        __syncthreads();
        if (tid == 0) {
            const int gtotal = lds[12] + lds[13] + lds[14] + lds[15];
            __hip_atomic_store(&gflags[g], FLAG_VALID | (unsigned)gtotal,
                               __ATOMIC_RELEASE, __HIP_MEMORY_SCOPE_AGENT);
        }
    }

    // Exclusive rank within block (local work; gives predecessors time).
    int incl = c;
#pragma unroll
    for (int off = 1; off < 64; off <<= 1) {
        const int u = __shfl_up(incl, off, 64);
        if (lane >= off) incl += u;
    }
    if (lane == 63) lds[4 + wave] = incl;
    __syncthreads();
    int waveEx = 0;
#pragma unroll
    for (int w = 0; w < 4; ++w) waveEx += (w < wave) ? lds[4 + w] : 0;
    int r = waveEx + incl - c;

    // Hierarchical lookback: full groups via gflags (1/thread), partial group
    // via level-0 flags (1/thread). Sequential depth ~2 dependent loads.
    int sum = 0;
    if (tid < g) {
        unsigned f = __hip_atomic_load(&gflags[tid], __ATOMIC_RELAXED,
                                       __HIP_MEMORY_SCOPE_AGENT);
        while (!(f & FLAG_VALID)) {
            __builtin_amdgcn_s_sleep(4);
            f = __hip_atomic_load(&gflags[tid], __ATOMIC_RELAXED,
                                  __HIP_MEMORY_SCOPE_AGENT);
        }
        sum = (int)(f & FLAG_MASK);
    }
    const int pCount = b - gBase;
    if (tid < pCount) {
        unsigned f = __hip_atomic_load(&flags[gBase + tid], __ATOMIC_RELAXED,
                                       __HIP_MEMORY_SCOPE_AGENT);
        while (!(f & FLAG_VALID)) {
            __builtin_amdgcn_s_sleep(2);
            f = __hip_atomic_load(&flags[gBase + tid], __ATOMIC_RELAXED,
                                  __HIP_MEMORY_SCOPE_AGENT);
        }
        sum += (int)(f & FLAG_MASK);
    }
#pragma unroll
    for (int off = 32; off > 0; off >>= 1) sum += __shfl_down(sum, off, 64);
    if (lane == 0) lds[8 + wave] = sum;
    __syncthreads();
    const int excl = lds[8] + lds[9] + lds[10] + lds[11];

    // Stage positives shifted by pad so the output body is 16B-aligned.
    const int pad = excl & 3;
    r += pad;
#pragma unroll
    for (int j = 0; j < VPT; ++j) {
        if (v[j] > 0.f) vals[r++] = v[j];
    }
    __syncthreads();

    // Vectorized store of positives: vals[k] <-> y[yb + k], yb = excl - pad.
    const int m = pad + total;
    const long long yb = (long long)excl - pad;
    const int nq = (m + 3) >> 2;
    for (int t = tid; t < nq; t += BLOCK) {
        const int k0 = 4 * t;
        if (k0 >= pad && k0 + 4 <= m) {
            *reinterpret_cast<float4*>(y + yb + k0) =
                *reinterpret_cast<const float4*>(&vals[k0]);
        } else {
            const int ks = (k0 < pad) ? pad : k0;
            const int ke = (k0 + 4 < m) ? k0 + 4 : m;
            for (int k = ks; k < ke; ++k) y[yb + k] = vals[k];
        }
    }

    // Fused zerofill: this block's zeros tile a slice of [count, n) from the
    // top down; regions are disjoint and cover [count, n) exactly.
    const int rem   = n - chunkBase;
    const int elems = rem < CHUNK ? rem : CHUNK;
    const int z     = elems - total;
    const long long zhi = (long long)n - (chunkBase - excl);
    const long long zlo = zhi - z;
    const long long za  = (zlo + 3) & ~3LL;    // first aligned quad start
    const long long zb  = zhi & ~3LL;          // last aligned quad end
    if (za >= zb) {
        for (long long j = zlo + tid; j < zhi; j += BLOCK) y[j] = 0.f;
    } else {
        if (tid < (int)(za - zlo)) y[zlo + tid] = 0.f;                     // head (<=3)
        if (tid >= 4 && tid - 4 < (int)(zhi - zb)) y[zb + tid - 4] = 0.f;  // tail (<=3)
        const int zq = (int)((zb - za) >> 2);
        const float4 zero = make_float4(0.f, 0.f, 0.f, 0.f);
        for (int t = tid; t < zq; t += BLOCK) {
            *reinterpret_cast<float4*>(y + za + 4 * t) = zero;
        }
    }

    if (b == numBlocks - 1 && tid == 0) {
        y[out_size - 1] = (float)(excl + total);
    }
}

extern "C" void kernel_launch(void* const* d_in, const int* in_sizes, int n_in,
                              void* d_out, int out_size, void* d_ws, size_t ws_size,
                              hipStream_t stream) {
    const float* x = (const float*)d_in[0];
    float* y = (float*)d_out;
    const int n = in_sizes[0];

    unsigned int* flags = (unsigned int*)d_ws;
    const int numBlocks = (n + CHUNK - 1) / CHUNK;          // 16384 for N=64M
    const int numGroups = (numBlocks + GROUP - 1) / GROUP;  // 64

    const int nWords = numBlocks + 2 * numGroups + 1;       // flags+gflags+gcount+ticket
    const int initBlocks = (nWords + BLOCK - 1) / BLOCK;
    k_init<<<initBlocks, BLOCK, 0, stream>>>(flags, nWords);
    k_compact<<<numBlocks, BLOCK, 0, stream>>>(x, n, numBlocks, numGroups, out_size, flags, y);
}

// Round 7
// 481.596 us; speedup vs baseline: 3.8191x; 3.8191x over previous
//
#include <hip/hip_runtime.h>

// Stable stream compaction: y[:count] = x[x>0] in original order, y[count:n]=0,
// y[out_size-1] = (float)count.
//
// reduce-then-scan, 3 kernels. Single-pass lookback is abandoned for good:
// measured R1=1956us (PRE chain), R4=995us (flat AGG, 134M flag loads),
// R5=1575us (hierarchical, 2-cacheline spin hotspot) vs ~190us kernel time
// here. Cross-XCD atomic visibility latency makes spin-waiting structurally
// bad on MI355X.
//
//   k_count   : per-block positive count, coalesced float4 loads (forward:
//               populates L3 with x, 256 MB = exactly L3 capacity)
//   k_scan    : single-block exclusive scan of 16384 block sums + count out
//   k_scatter : REVERSE chunk order (LRU-friendly restream of exactly-capacity
//               working set) + ALL y stores NONTEMPORAL (nt flag: do not
//               allocate in LLC) so the 257 MB output stream doesn't evict x.
//               Together these aim the x re-read at L3 instead of HBM.
//
// NOTE: __builtin_nontemporal_store needs a clang vector type, not HIP's
// struct float4 — use ext_vector_type(4).

#define BLOCK 256
#define VPT 16               // elems per thread (contiguous, scatter only)
#define CHUNK (BLOCK * VPT)  // 4096
#define SCAN_THREADS 1024
#define SCAN_VPT 16          // scan supports up to 16384 block sums

typedef float floatx4 __attribute__((ext_vector_type(4)));

__global__ void __launch_bounds__(BLOCK)
k_count(const float* __restrict__ x, int n, int* __restrict__ blockSums) {
    const int tid = threadIdx.x;
    const long long chunkBase = (long long)blockIdx.x * CHUNK;
    int cnt = 0;
    if (chunkBase + CHUNK <= n) {
        // coalesced: lane-contiguous float4, 4 rounds of 1024 elems
        const float* p = x + chunkBase + tid * 4;
#pragma unroll
        for (int it = 0; it < 4; ++it) {
            const float4 v = *reinterpret_cast<const float4*>(p + it * (BLOCK * 4));
            cnt += (v.x > 0.f) + (v.y > 0.f) + (v.z > 0.f) + (v.w > 0.f);
        }
    } else {
        const long long lim = (chunkBase + CHUNK < n) ? chunkBase + CHUNK : n;
        for (long long j = chunkBase + tid; j < lim; j += BLOCK) cnt += (x[j] > 0.f);
    }
#pragma unroll
    for (int off = 32; off > 0; off >>= 1) cnt += __shfl_down(cnt, off, 64);
    __shared__ int lds[4];
    if ((tid & 63) == 0) lds[tid >> 6] = cnt;
    __syncthreads();
    if (tid == 0) blockSums[blockIdx.x] = lds[0] + lds[1] + lds[2] + lds[3];
}

// Single-block exclusive scan of blockSums (numBlocks <= SCAN_THREADS*SCAN_VPT).
__global__ void k_scan(int* __restrict__ sums, int numBlocks,
                       int* __restrict__ countOut, float* __restrict__ countOutF) {
    __shared__ int lds[32];
    const int tid  = threadIdx.x;
    const int lane = tid & 63;
    const int wave = tid >> 6;   // 16 waves

    int vals[SCAN_VPT];
    const int base = tid * SCAN_VPT;
    int local = 0;
#pragma unroll
    for (int j = 0; j < SCAN_VPT; ++j) {
        const int i = base + j;
        const int v = (i < numBlocks) ? sums[i] : 0;
        vals[j] = local;         // thread-local exclusive
        local += v;
    }
    int incl = local;
#pragma unroll
    for (int off = 1; off < 64; off <<= 1) {
        const int y = __shfl_up(incl, off, 64);
        if (lane >= off) incl += y;
    }
    if (lane == 63) lds[wave] = incl;
    __syncthreads();
    if (wave == 0 && lane < 16) {
        int w = lds[lane];
#pragma unroll
        for (int off = 1; off < 16; off <<= 1) {
            const int y = __shfl_up(w, off, 16);
            if ((lane & 15) >= off) w += y;
        }
        lds[16 + lane] = w;      // inclusive wave prefix
    }
    __syncthreads();
    const int waveEx   = (wave == 0) ? 0 : lds[16 + wave - 1];
    const int threadEx = waveEx + incl - local;
#pragma unroll
    for (int j = 0; j < SCAN_VPT; ++j) {
        const int i = base + j;
        if (i < numBlocks) sums[i] = threadEx + vals[j];
    }
    if (tid == SCAN_THREADS - 1) {
        const int total = waveEx + incl;
        *countOut  = total;
        *countOutF = (float)total;
    }
}

// exclusive block scan over 256 threads (4 waves); returns exclusive rank,
// sets *blockTotal. lds must have >= 9 ints.
__device__ __forceinline__ int block_scan_excl_256(int val, int* lds, int* blockTotal) {
    const int tid  = threadIdx.x;
    const int lane = tid & 63;
    const int wave = tid >> 6;
    int incl = val;
#pragma unroll
    for (int off = 1; off < 64; off <<= 1) {
        const int y = __shfl_up(incl, off, 64);
        if (lane >= off) incl += y;
    }
    if (lane == 63) lds[wave] = incl;
    __syncthreads();
    if (tid == 0) {
        const int s0 = lds[0], s1 = lds[1], s2 = lds[2], s3 = lds[3];
        lds[4] = 0; lds[5] = s0; lds[6] = s0 + s1; lds[7] = s0 + s1 + s2;
        lds[8] = s0 + s1 + s2 + s3;
    }
    __syncthreads();
    const int ex = lds[4 + wave] + incl - val;
    *blockTotal = lds[8];
    return ex;
}

__global__ void __launch_bounds__(BLOCK)
k_scatter(const float* __restrict__ x, int n, int numBlocks,
          const int* __restrict__ blockOffsets, float* __restrict__ y) {
    __shared__ __align__(16) float vals[CHUNK + 4];  // +pad (up to 3) for aligned output
    __shared__ int scan_lds[9];
    const int tid = threadIdx.x;
    const int chunk = numBlocks - 1 - blockIdx.x;    // reverse order for L3 reuse
    const int chunkBase = chunk * CHUNK;
    const long long tbase = (long long)chunkBase + tid * VPT;

    float v[VPT];
    if ((long long)chunkBase + CHUNK <= n) {
#pragma unroll
        for (int k = 0; k < 4; ++k) {
            const float4 f = *reinterpret_cast<const float4*>(x + tbase + 4 * k);
            v[4 * k + 0] = f.x; v[4 * k + 1] = f.y; v[4 * k + 2] = f.z; v[4 * k + 3] = f.w;
        }
    } else {
#pragma unroll
        for (int j = 0; j < VPT; ++j)
            v[j] = (tbase + j < n) ? x[tbase + j] : 0.f;
    }

    int c = 0;
#pragma unroll
    for (int j = 0; j < VPT; ++j) c += (v[j] > 0.f);

    int total;
    int r = block_scan_excl_256(c, scan_lds, &total);

    const int excl = blockOffsets[chunk];
    const int pad  = excl & 3;                 // stage shifted so output is 16B-aligned

    r += pad;
#pragma unroll
    for (int j = 0; j < VPT; ++j) {
        if (v[j] > 0.f) vals[r++] = v[j];
    }
    __syncthreads();

    // Vectorized NONTEMPORAL store of positives: vals[k] <-> y[yb + k],
    // yb = excl - pad (mod 4 == 0). nt: don't allocate y lines in LLC.
    const int m = pad + total;
    const long long yb = (long long)excl - pad;
    const int nq = (m + 3) >> 2;
    for (int t = tid; t < nq; t += BLOCK) {
        const int k0 = 4 * t;
        if (k0 >= pad && k0 + 4 <= m) {
            __builtin_nontemporal_store(
                *reinterpret_cast<const floatx4*>(&vals[k0]),
                reinterpret_cast<floatx4*>(y + yb + k0));
        } else {
            const int ks = (k0 < pad) ? pad : k0;
            const int ke = (k0 + 4 < m) ? k0 + 4 : m;
            for (int k = ks; k < ke; ++k)
                __builtin_nontemporal_store(vals[k], y + yb + k);
        }
    }

    // Fused zerofill (nontemporal): this block's zeros tile a slice of
    // [count, n) from the top down; regions are disjoint and cover it exactly.
    const int rem   = n - chunkBase;
    const int elems = rem < CHUNK ? rem : CHUNK;
    const int z     = elems - total;
    const long long zhi = (long long)n - (chunkBase - excl);
    const long long zlo = zhi - z;
    const long long za  = (zlo + 3) & ~3LL;    // first aligned quad start
    const long long zb  = zhi & ~3LL;          // last aligned quad end
    if (za >= zb) {
        for (long long j = zlo + tid; j < zhi; j += BLOCK)
            __builtin_nontemporal_store(0.f, y + j);
    } else {
        if (tid < (int)(za - zlo))
            __builtin_nontemporal_store(0.f, y + zlo + tid);               // head (<=3)
        if (tid >= 4 && tid - 4 < (int)(zhi - zb))
            __builtin_nontemporal_store(0.f, y + zb + tid - 4);            // tail (<=3)
        const int zq = (int)((zb - za) >> 2);
        const floatx4 zero = (floatx4)(0.f);
        for (int t = tid; t < zq; t += BLOCK) {
            __builtin_nontemporal_store(zero, reinterpret_cast<floatx4*>(y + za + 4 * t));
        }
    }
}

extern "C" void kernel_launch(void* const* d_in, const int* in_sizes, int n_in,
                              void* d_out, int out_size, void* d_ws, size_t ws_size,
                              hipStream_t stream) {
    const float* x = (const float*)d_in[0];
    float* y = (float*)d_out;
    const int n = in_sizes[0];

    int* blockSums = (int*)d_ws;
    const int numBlocks = (n + CHUNK - 1) / CHUNK;   // 16384 for N=64M
    int* countPtr = blockSums + numBlocks;

    k_count<<<numBlocks, BLOCK, 0, stream>>>(x, n, blockSums);
    k_scan<<<1, SCAN_THREADS, 0, stream>>>(blockSums, numBlocks,
                                           countPtr, y + (out_size - 1));
    k_scatter<<<numBlocks, BLOCK, 0, stream>>>(x, n, numBlocks, blockSums, y);
}